// Round 9
// baseline (296.249 us; speedup 1.0000x reference)
//
#include <hip/hip_runtime.h>
#include <hip/hip_bf16.h>

// Problem dims
#define B_  32
#define C_  16
#define Hh  64
#define Ww  64
#define O_  256
#define Kk  5
#define Ho_ 60
#define Wo_ 60
#define Dd  400                 // C*K*K
#define Nn  (B_*Ho_*Wo_)        // 115200
#define NY  ((size_t)B_*O_*Ho_*Wo_)  // 29491200
#define ACAP 16384              // ambiguous-row list capacity
#define TAU 2.5e-4f             // top-2 gap threshold (bf16x3 max err ~1e-5, 25x margin)

typedef float f4 __attribute__((ext_vector_type(4)));
typedef float f32x4 __attribute__((ext_vector_type(4)));
typedef unsigned int u32x2 __attribute__((ext_vector_type(2)));
typedef unsigned int u32x4 __attribute__((ext_vector_type(4)));
typedef __bf16 bf16x8 __attribute__((ext_vector_type(8)));

static __device__ __forceinline__ void bf16split(float v, unsigned short& h, unsigned short& l) {
    __hip_bfloat16 bh = __float2bfloat16(v);
    float vh = __bfloat162float(bh);
    __hip_bfloat16 bl = __float2bfloat16(v - vh);
    h = __builtin_bit_cast(unsigned short, bh);
    l = __builtin_bit_cast(unsigned short, bl);
}

// ---- prep: pack w into per-tap coalesced MFMA-B layout, bf16 hi/lo planes ----
// wpk[(jc*3+s)][wv][t][q][r][j] (u16): o = 64wv+16t+r, k-slot = 8q+j -> g = 32s+8q+j,
// value = w[o][g*5 + jc] (g<80 else 0). Lane (q,r) reads its 16B at base + L*16.
__global__ void prep_kernel(const float* __restrict__ w, unsigned short* __restrict__ wpkH,
                            unsigned short* __restrict__ wpkL, int* __restrict__ count,
                            int* __restrict__ acnt) {
    const int bi = blockIdx.x;          // 0..59
    const int wv = bi & 3;
    const int u  = bi >> 2;             // 0..14 = jc*3 + s
    const int jc = u / 3, s = u - (u / 3) * 3;
    const int tid = threadIdx.x;
    const int t = tid >> 6, q = (tid >> 4) & 3, r = tid & 15;
    const int o = 64 * wv + 16 * t + r;
    unsigned short h[8], l[8];
    #pragma unroll
    for (int j = 0; j < 8; ++j) {
        int gk = 32 * s + 8 * q + j;
        float v = (gk < 80) ? w[o * Dd + gk * 5 + jc] : 0.f;
        bf16split(v, h[j], l[j]);
    }
    const size_t base = (size_t)u * 8192 + wv * 2048 + t * 512 + q * 128 + r * 8;  // u16 units
    u32x4 ph = { (unsigned)h[0] | ((unsigned)h[1] << 16), (unsigned)h[2] | ((unsigned)h[3] << 16),
                 (unsigned)h[4] | ((unsigned)h[5] << 16), (unsigned)h[6] | ((unsigned)h[7] << 16) };
    u32x4 pl = { (unsigned)l[0] | ((unsigned)l[1] << 16), (unsigned)l[2] | ((unsigned)l[3] << 16),
                 (unsigned)l[4] | ((unsigned)l[5] << 16), (unsigned)l[6] | ((unsigned)l[7] << 16) };
    *reinterpret_cast<u32x4*>(wpkH + base) = ph;
    *reinterpret_cast<u32x4*>(wpkL + base) = pl;
    if (bi == 0) { count[tid] = 0; if (tid == 0) *acnt = 0; }
}

// ---- phase 1: tap-split bf16x3 MFMA conv + top2 argmax + winner/ambig append ----
// grid 1920 (b,ho); 4 waves; wave wv: o in [64wv,64wv+64); block covers wo 0..63 (4 pt tiles).
// A fragment: one ds_read_b128 per plane from transposed LDS xT[v][g] (208B row stride).
__launch_bounds__(256, 5)
__global__ void conv_mfma_kernel(const float* __restrict__ x, const unsigned short* __restrict__ wpkH,
                                 const unsigned short* __restrict__ wpkL, float* __restrict__ y,
                                 int* __restrict__ count, int* __restrict__ lw_n,
                                 float* __restrict__ lw_s, int* __restrict__ acnt,
                                 int* __restrict__ ambig, int cap) {
    __shared__ __align__(16) unsigned short xT[2 * 7072];   // [plane][v 0..67][g 0..103]
    __shared__ float wm1[4][64], wm2[4][64];
    __shared__ float rowM1[64];

    const int tid = threadIdx.x;
    const int L = tid & 63, wv = tid >> 6;
    const int q = L >> 4, r = L & 15;
    const int b = blockIdx.x / Ho_, ho = blockIdx.x % Ho_;

    // ---- zero pad regions (disjoint from staged region): cols 80..95 all rows; rows 64..67 cols 0..79
    {
        u32x4 z = { 0, 0, 0, 0 };
        for (int id = tid; id < 272; id += 256) {
            int plane = id & 1, rem = id >> 1, row = rem >> 1, half = rem & 1;
            *reinterpret_cast<u32x4*>(&xT[plane * 7072 + row * 104 + 80 + half * 8]) = z;
        }
        if (tid < 80) {
            int plane = tid / 40, rem = tid % 40, row = 64 + rem / 10, blk = rem % 10;
            *reinterpret_cast<u32x4*>(&xT[plane * 7072 + row * 104 + blk * 8]) = z;
        }
    }

    // ---- stage x patch transposed, column-gather:
    // thread (v = tid&63, seg = tid>>6) covers g in [seg*20, seg*20+20), 4-g groups -> b64 writes
    {
        const float* xb = x + (size_t)b * (C_ * Hh * Ww);
        const int v = tid & 63;
        const int seg = tid >> 6;
        const int segc = seg * 4;                 // c base: 20 g = 4 channels exactly
        #pragma unroll
        for (int qg = 0; qg < 5; ++qg) {
            unsigned short h[4], l[4];
            #pragma unroll
            for (int gg = 0; gg < 4; ++gg) {
                const int k = qg * 4 + gg;        // 0..19, compile-time
                const int kc = k / 5, ki = k % 5; // compile-time
                float val = xb[((segc + kc) * Hh + ho + ki) * Ww + v];
                bf16split(val, h[gg], l[gg]);
            }
            const int g0 = seg * 20 + qg * 4;
            u32x2 ph = { (unsigned)h[0] | ((unsigned)h[1] << 16),
                         (unsigned)h[2] | ((unsigned)h[3] << 16) };
            u32x2 pl = { (unsigned)l[0] | ((unsigned)l[1] << 16),
                         (unsigned)l[2] | ((unsigned)l[3] << 16) };
            *reinterpret_cast<u32x2*>(&xT[v * 104 + g0]) = ph;
            *reinterpret_cast<u32x2*>(&xT[7072 + v * 104 + g0]) = pl;
        }
    }

    f32x4 acc[4][4];
    #pragma unroll
    for (int pt = 0; pt < 4; ++pt)
        #pragma unroll
        for (int t = 0; t < 4; ++t) { acc[pt][t].x = 0.f; acc[pt][t].y = 0.f; acc[pt][t].z = 0.f; acc[pt][t].w = 0.f; }

    __syncthreads();

    const unsigned short* bh0 = wpkH + wv * 2048 + (size_t)L * 8;
    const unsigned short* bl0 = wpkL + wv * 2048 + (size_t)L * 8;
    const int abase = r * 104 + q * 8;       // u16 units; + jc*104 + s*32 + pt*1664 (+7072 lo plane)

    #pragma unroll 1
    for (int jc = 0; jc < 5; ++jc) {
        #pragma unroll 1
        for (int s = 0; s < 3; ++s) {
            const unsigned short* bhp = bh0 + (jc * 3 + s) * 8192;
            const unsigned short* blp = bl0 + (jc * 3 + s) * 8192;
            u32x4 BH[4], BL[4];
            #pragma unroll
            for (int t = 0; t < 4; ++t) {
                BH[t] = *reinterpret_cast<const u32x4*>(bhp + t * 512);
                BL[t] = *reinterpret_cast<const u32x4*>(blp + t * 512);
            }
            const int ao = abase + jc * 104 + s * 32;
            #pragma unroll
            for (int pt = 0; pt < 4; ++pt) {
                u32x4 AHu = *reinterpret_cast<const u32x4*>(&xT[ao + pt * 1664]);
                u32x4 ALu = *reinterpret_cast<const u32x4*>(&xT[7072 + ao + pt * 1664]);
                bf16x8 Ah = __builtin_bit_cast(bf16x8, AHu);
                bf16x8 Al = __builtin_bit_cast(bf16x8, ALu);
                #pragma unroll
                for (int t = 0; t < 4; ++t) {
                    bf16x8 Bh = __builtin_bit_cast(bf16x8, BH[t]);
                    bf16x8 Bl = __builtin_bit_cast(bf16x8, BL[t]);
                    acc[pt][t] = __builtin_amdgcn_mfma_f32_16x16x32_bf16(Ah, Bh, acc[pt][t], 0, 0, 0);
                    acc[pt][t] = __builtin_amdgcn_mfma_f32_16x16x32_bf16(Ah, Bl, acc[pt][t], 0, 0, 0);
                    acc[pt][t] = __builtin_amdgcn_mfma_f32_16x16x32_bf16(Al, Bh, acc[pt][t], 0, 0, 0);
                }
            }
        }
    }

    // ---- per-row top-2 (wave-local over 64 o's, then cross-wave via LDS)
    #pragma unroll
    for (int pt = 0; pt < 4; ++pt) {
        #pragma unroll
        for (int i = 0; i < 4; ++i) {
            float a0 = acc[pt][0][i], a1 = acc[pt][1][i], a2 = acc[pt][2][i], a3 = acc[pt][3][i];
            float m1 = fmaxf(a0, a1), m2 = fminf(a0, a1);
            m2 = fmaxf(m2, fminf(m1, a2)); m1 = fmaxf(m1, a2);
            m2 = fmaxf(m2, fminf(m1, a3)); m1 = fmaxf(m1, a3);
            #pragma unroll
            for (int off = 1; off <= 8; off <<= 1) {
                float o1 = __shfl_xor(m1, off), o2 = __shfl_xor(m2, off);
                m2 = fmaxf(fminf(m1, o1), fmaxf(m2, o2));
                m1 = fmaxf(m1, o1);
            }
            if (r == 0) { int p = 16 * pt + 4 * q + i; wm1[wv][p] = m1; wm2[wv][p] = m2; }
        }
    }
    __syncthreads();
    if (tid < 64) {
        const int p = tid;
        float M1 = wm1[0][p], M2 = wm2[0][p];
        #pragma unroll
        for (int w2 = 1; w2 < 4; ++w2) {
            float c1 = wm1[w2][p], c2 = wm2[w2][p];
            M2 = fmaxf(fminf(M1, c1), fmaxf(M2, c2));
            M1 = fmaxf(M1, c1);
        }
        bool amb = (M1 - M2) < TAU;
        if (amb && p < Wo_) {
            int n = (b * Ho_ + ho) * Wo_ + p;
            int pos = atomicAdd(acnt, 1);
            if (pos < ACAP) ambig[pos] = n;
        }
        rowM1[p] = amb ? __builtin_inff() : M1;   // INF suppresses appends for ambiguous rows
    }
    __syncthreads();

    // ---- winner appends (exact equality vs block max; ties append all, like s==s.max())
    #pragma unroll
    for (int pt = 0; pt < 4; ++pt) {
        #pragma unroll
        for (int i = 0; i < 4; ++i) {
            const int p = 16 * pt + 4 * q + i;
            const float M = rowM1[p];
            if (p < Wo_) {
                const int n = (b * Ho_ + ho) * Wo_ + p;
                #pragma unroll
                for (int t = 0; t < 4; ++t) {
                    float v = acc[pt][t][i];
                    if (v == M) {
                        int o = 64 * wv + 16 * t + r;
                        int pos = atomicAdd(&count[o], 1);
                        if (pos < cap) { lw_n[o * cap + pos] = n; lw_s[o * cap + pos] = v; }
                    }
                }
            }
        }
    }

    // ---- y stores: acc reg vector = 4 consecutive wo for one o -> dwordx4
    #pragma unroll
    for (int pt = 0; pt < 4; ++pt) {
        const int wo = 16 * pt + 4 * q;
        if (wo < Wo_) {                       // skips (pt=3,q=3) = wo 60..63
            #pragma unroll
            for (int t = 0; t < 4; ++t) {
                const int o = 64 * wv + 16 * t + r;
                f4 v = { acc[pt][t].x, acc[pt][t].y, acc[pt][t].z, acc[pt][t].w };
                *reinterpret_cast<f4*>(y + ((size_t)(b * O_ + o) * Ho_ + ho) * (size_t)Wo_ + wo) = v;
            }
        }
    }
}

// ---- fallback: exact fp32 re-resolve of ambiguous rows ----
__global__ void fallback_kernel(const float* __restrict__ x, const float* __restrict__ w,
                                const int* __restrict__ acnt, const int* __restrict__ ambig,
                                int* __restrict__ count, int* __restrict__ lw_n,
                                float* __restrict__ lw_s, int cap) {
    __shared__ float xrow[Dd];
    __shared__ float red[256];
    int cnt = *acnt; if (cnt > ACAP) cnt = ACAP;
    for (int idx = blockIdx.x; idx < cnt; idx += gridDim.x) {
        const int n = ambig[idx];
        const int bb = n / 3600, rem = n % 3600, hh = rem / 60, ww2 = rem % 60;
        for (int k = threadIdx.x; k < Dd; k += 256) {
            int c = k / 25, rr = k % 25, i = rr / 5, j = rr % 5;
            xrow[k] = x[(((size_t)bb * C_ + c) * Hh + hh + i) * Ww + ww2 + j];
        }
        __syncthreads();
        const int o = threadIdx.x;
        const float* wr = w + (size_t)o * Dd;
        float s = 0.f;
        #pragma unroll 4
        for (int k = 0; k < Dd; ++k) s = fmaf(xrow[k], wr[k], s);
        red[o] = s;
        __syncthreads();
        #pragma unroll
        for (int st = 128; st >= 1; st >>= 1) {
            if (o < st) red[o] = fmaxf(red[o], red[o + st]);
            __syncthreads();
        }
        const float mx = red[0];
        if (s == mx) {
            int pos = atomicAdd(&count[o], 1);
            if (pos < cap) { lw_n[o * cap + pos] = n; lw_s[o * cap + pos] = s; }
        }
        __syncthreads();
    }
}

// ---- phase 2a: per-slice partial sums (4 slices per o) ----
__global__ void delta_part_kernel(const float* __restrict__ x,
                                  const int* __restrict__ count, const int* __restrict__ lw_n,
                                  const float* __restrict__ lw_s, float* __restrict__ partial,
                                  float* __restrict__ ssum_part, int cap) {
    const int o   = blockIdx.x >> 2;
    const int sl  = blockIdx.x & 3;
    const int tid = threadIdx.x;
    int cnt = count[o]; if (cnt > cap) cnt = cap;
    const int e0 = (cnt * sl) >> 2;
    const int e1 = (cnt * (sl + 1)) >> 2;

    const int d0 = tid;
    const int c0 = d0 / 25, r0 = d0 % 25, i0 = r0 / 5, j0 = r0 % 5;
    const bool has1 = (tid < Dd - 256);
    const int dd1 = has1 ? tid + 256 : 0;
    const int c1 = dd1 / 25, r1 = dd1 % 25, i1 = r1 / 5, j1 = r1 % 5;

    const int* ln = lw_n + (size_t)o * cap;
    const float* ls = lw_s + (size_t)o * cap;

    float acc0 = 0.f, acc1 = 0.f, ssum = 0.f;
    int   nn = (e0 < e1) ? ln[e0] : 0;
    float sn = (e0 < e1) ? ls[e0] : 0.f;
    for (int e = e0; e < e1; ++e) {
        const int n = nn; const float s = sn;
        if (e + 1 < e1) { nn = ln[e + 1]; sn = ls[e + 1]; }
        const int bb = n / 3600;
        const int rem = n - bb * 3600;
        const int hh = rem / 60;
        const int ww2 = rem - hh * 60;
        ssum += s;
        const float* xb = x + (size_t)bb * (C_ * Hh * Ww);
        acc0 += s * xb[(c0 * Hh + hh + i0) * Ww + ww2 + j0];
        if (has1) acc1 += s * xb[(c1 * Hh + hh + i1) * Ww + ww2 + j1];
    }
    float* pp = partial + ((size_t)o * 4 + sl) * Dd;
    pp[tid] = acc0;
    if (has1) pp[tid + 256] = acc1;
    if (tid == 0) ssum_part[o * 4 + sl] = ssum;
}

// ---- phase 2b: reduce partials, apply -ssum/N * w ----
__global__ void delta_reduce_kernel(const float* __restrict__ w, const float* __restrict__ partial,
                                    const float* __restrict__ ssum_part,
                                    float* __restrict__ dout) {
    const int o = blockIdx.x, tid = threadIdx.x;
    const float ssum = ssum_part[o * 4] + ssum_part[o * 4 + 1]
                     + ssum_part[o * 4 + 2] + ssum_part[o * 4 + 3];
    const float invN = 1.0f / (float)Nn;
    const float* pp = partial + (size_t)o * 4 * Dd;
    float a0 = pp[tid] + pp[Dd + tid] + pp[2 * Dd + tid] + pp[3 * Dd + tid];
    dout[NY + (size_t)o * Dd + tid] = a0 * invN - ssum * invN * w[o * Dd + tid];
    if (tid < Dd - 256) {
        const int t2 = tid + 256;
        float a1 = pp[t2] + pp[Dd + t2] + pp[2 * Dd + t2] + pp[3 * Dd + t2];
        dout[NY + (size_t)o * Dd + t2] = a1 * invN - ssum * invN * w[o * Dd + t2];
    }
}

extern "C" void kernel_launch(void* const* d_in, const int* in_sizes, int n_in,
                              void* d_out, int out_size, void* d_ws, size_t ws_size,
                              hipStream_t stream) {
    (void)in_sizes; (void)n_in; (void)out_size;
    const float* x = (const float*)d_in[0];
    const float* w = (const float*)d_in[1];
    float* out = (float*)d_out;

    char* ws = (char*)d_ws;
    int*            count     = (int*)ws;                          // @0         (1,024 B)
    int*            acnt      = (int*)(ws + 1024);                 // @1,024     (64 B)
    int*            ambig     = (int*)(ws + 1088);                 // @1,088     (65,536 B)
    unsigned short* wpkH      = (unsigned short*)(ws + 66624);     // @66,624    (245,760 B)
    unsigned short* wpkL      = (unsigned short*)(ws + 312384);    // @312,384   (245,760 B)
    float*          partial   = (float*)(ws + 558144);             // @558,144   (1,638,400 B)
    float*          ssum_part = (float*)(ws + 2196544);            // @2,196,544 (4,096 B)
    const size_t base = 2200640;

    size_t avail = (ws_size > base) ? (ws_size - base) : 0;
    long long cap_ll = (long long)(avail / ((size_t)O_ * 8));
    int cap = (int)(cap_ll > 4096 ? 4096 : (cap_ll < 1 ? 1 : cap_ll));

    int*   lw_n = (int*)(ws + base);
    float* lw_s = (float*)(ws + base + (size_t)O_ * cap * 4);

    prep_kernel<<<dim3(60), dim3(256), 0, stream>>>(w, wpkH, wpkL, count, acnt);
    conv_mfma_kernel<<<dim3(B_ * Ho_), dim3(256), 0, stream>>>(x, wpkH, wpkL, out, count, lw_n, lw_s,
                                                               acnt, ambig, cap);
    fallback_kernel<<<dim3(256), dim3(256), 0, stream>>>(x, w, acnt, ambig, count, lw_n, lw_s, cap);
    delta_part_kernel<<<dim3(O_ * 4), dim3(256), 0, stream>>>(x, count, lw_n, lw_s, partial, ssum_part, cap);
    delta_reduce_kernel<<<dim3(O_), dim3(256), 0, stream>>>(w, partial, ssum_part, out);
}

// Round 10
// 251.816 us; speedup vs baseline: 1.1764x; 1.1764x over previous
//
#include <hip/hip_runtime.h>
#include <hip/hip_bf16.h>

// Problem dims
#define B_  32
#define C_  16
#define Hh  64
#define Ww  64
#define O_  256
#define Kk  5
#define Ho_ 60
#define Wo_ 60
#define Dd  400                 // C*K*K
#define Nn  (B_*Ho_*Wo_)        // 115200
#define NY  ((size_t)B_*O_*Ho_*Wo_)  // 29491200
#define ACAP 16384              // ambiguous-row list capacity
#define TAU 2.5e-4f             // top-2 gap threshold (bf16x3 max err ~1e-5, 25x margin)

typedef float f4 __attribute__((ext_vector_type(4)));
typedef float f32x4 __attribute__((ext_vector_type(4)));
typedef unsigned int u32x2 __attribute__((ext_vector_type(2)));
typedef unsigned int u32x4 __attribute__((ext_vector_type(4)));
typedef __bf16 bf16x8 __attribute__((ext_vector_type(8)));

static __device__ __forceinline__ void bf16split(float v, unsigned short& h, unsigned short& l) {
    __hip_bfloat16 bh = __float2bfloat16(v);
    float vh = __bfloat162float(bh);
    __hip_bfloat16 bl = __float2bfloat16(v - vh);
    h = __builtin_bit_cast(unsigned short, bh);
    l = __builtin_bit_cast(unsigned short, bl);
}

// ---- prep: pack w into per-tap coalesced MFMA-B layout, bf16 hi/lo planes ----
// wpk[(jc*3+s)][wv][t][q][r][j] (u16): o = 64wv+16t+r, k-slot = 8q+j -> g = 32s+8q+j,
// value = w[o][g*5 + jc] (g<80 else 0). Lane (q,r) reads its 16B at base + L*16.
__global__ void prep_kernel(const float* __restrict__ w, unsigned short* __restrict__ wpkH,
                            unsigned short* __restrict__ wpkL, int* __restrict__ count,
                            int* __restrict__ acnt) {
    const int bi = blockIdx.x;          // 0..59
    const int wv = bi & 3;
    const int u  = bi >> 2;             // 0..14 = jc*3 + s
    const int jc = u / 3, s = u - (u / 3) * 3;
    const int tid = threadIdx.x;
    const int t = tid >> 6, q = (tid >> 4) & 3, r = tid & 15;
    const int o = 64 * wv + 16 * t + r;
    unsigned short h[8], l[8];
    #pragma unroll
    for (int j = 0; j < 8; ++j) {
        int gk = 32 * s + 8 * q + j;
        float v = (gk < 80) ? w[o * Dd + gk * 5 + jc] : 0.f;
        bf16split(v, h[j], l[j]);
    }
    const size_t base = (size_t)u * 8192 + wv * 2048 + t * 512 + q * 128 + r * 8;  // u16 units
    u32x4 ph = { (unsigned)h[0] | ((unsigned)h[1] << 16), (unsigned)h[2] | ((unsigned)h[3] << 16),
                 (unsigned)h[4] | ((unsigned)h[5] << 16), (unsigned)h[6] | ((unsigned)h[7] << 16) };
    u32x4 pl = { (unsigned)l[0] | ((unsigned)l[1] << 16), (unsigned)l[2] | ((unsigned)l[3] << 16),
                 (unsigned)l[4] | ((unsigned)l[5] << 16), (unsigned)l[6] | ((unsigned)l[7] << 16) };
    *reinterpret_cast<u32x4*>(wpkH + base) = ph;
    *reinterpret_cast<u32x4*>(wpkL + base) = pl;
    if (bi == 0) { count[tid] = 0; if (tid == 0) *acnt = 0; }
}

// ---- phase 1: tap-split bf16x3 MFMA conv + top2 argmax + winner/ambig append ----
// grid 1920 (b,ho); 4 waves; wave wv: o in [64wv,64wv+64); block covers wo 0..63 (4 pt tiles).
// B (weights) register-double-buffered with 1-step-ahead prefetch from L2; A single-buffered
// from transposed LDS xT[v][g]. 15-step loop fully unrolled -> all indices compile-time.
__launch_bounds__(256, 3)
__global__ void conv_mfma_kernel(const float* __restrict__ x, const unsigned short* __restrict__ wpkH,
                                 const unsigned short* __restrict__ wpkL, float* __restrict__ y,
                                 int* __restrict__ count, int* __restrict__ lw_n,
                                 float* __restrict__ lw_s, int* __restrict__ acnt,
                                 int* __restrict__ ambig, int cap) {
    __shared__ __align__(16) unsigned short xT[2 * 7072];   // [plane][v 0..67][g 0..103]
    __shared__ float wm1[4][64], wm2[4][64];
    __shared__ float rowM1[64];

    const int tid = threadIdx.x;
    const int L = tid & 63, wv = tid >> 6;
    const int q = L >> 4, r = L & 15;
    const int b = blockIdx.x / Ho_, ho = blockIdx.x % Ho_;

    // ---- zero pad regions: cols 80..95 all rows; rows 64..67 cols 0..79
    {
        u32x4 z = { 0, 0, 0, 0 };
        for (int id = tid; id < 272; id += 256) {
            int plane = id & 1, rem = id >> 1, row = rem >> 1, half = rem & 1;
            *reinterpret_cast<u32x4*>(&xT[plane * 7072 + row * 104 + 80 + half * 8]) = z;
        }
        if (tid < 80) {
            int plane = tid / 40, rem = tid % 40, row = 64 + rem / 10, blk = rem % 10;
            *reinterpret_cast<u32x4*>(&xT[plane * 7072 + row * 104 + blk * 8]) = z;
        }
    }

    // ---- stage x patch transposed, column-gather:
    // thread (v = tid&63, seg = tid>>6) covers g in [seg*20, seg*20+20), 4-g groups -> b64 writes
    {
        const float* xb = x + (size_t)b * (C_ * Hh * Ww);
        const int v = tid & 63;
        const int seg = tid >> 6;
        const int segc = seg * 4;                 // c base: 20 g = 4 channels exactly
        #pragma unroll
        for (int qg = 0; qg < 5; ++qg) {
            unsigned short h[4], l[4];
            #pragma unroll
            for (int gg = 0; gg < 4; ++gg) {
                const int k = qg * 4 + gg;        // 0..19, compile-time
                const int kc = k / 5, ki = k % 5; // compile-time
                float val = xb[((segc + kc) * Hh + ho + ki) * Ww + v];
                bf16split(val, h[gg], l[gg]);
            }
            const int g0 = seg * 20 + qg * 4;
            u32x2 ph = { (unsigned)h[0] | ((unsigned)h[1] << 16),
                         (unsigned)h[2] | ((unsigned)h[3] << 16) };
            u32x2 pl = { (unsigned)l[0] | ((unsigned)l[1] << 16),
                         (unsigned)l[2] | ((unsigned)l[3] << 16) };
            *reinterpret_cast<u32x2*>(&xT[v * 104 + g0]) = ph;
            *reinterpret_cast<u32x2*>(&xT[7072 + v * 104 + g0]) = pl;
        }
    }

    f32x4 acc[4][4];
    #pragma unroll
    for (int pt = 0; pt < 4; ++pt)
        #pragma unroll
        for (int t = 0; t < 4; ++t) { acc[pt][t].x = 0.f; acc[pt][t].y = 0.f; acc[pt][t].z = 0.f; acc[pt][t].w = 0.f; }

    __syncthreads();

    const unsigned short* bh0 = wpkH + wv * 2048 + (size_t)L * 8;
    const unsigned short* bl0 = wpkL + wv * 2048 + (size_t)L * 8;
    const int abase = r * 104 + q * 8;       // u16 units; + (u/3)*104 + (u%3)*32 + pt*1664

    // B double buffers (named; selection is compile-time under full unroll)
    u32x4 B0H[4], B0L[4], B1H[4], B1L[4];
    #pragma unroll
    for (int t = 0; t < 4; ++t) {
        B0H[t] = *reinterpret_cast<const u32x4*>(bh0 + t * 512);
        B0L[t] = *reinterpret_cast<const u32x4*>(bl0 + t * 512);
    }

    #pragma unroll
    for (int u = 0; u < 15; ++u) {
        u32x4* BH = (u & 1) ? B1H : B0H;
        u32x4* BL = (u & 1) ? B1L : B0L;
        u32x4* NH = (u & 1) ? B0H : B1H;
        u32x4* NL = (u & 1) ? B0L : B1L;
        if (u < 14) {                         // prefetch next step's B into the other buffer
            const unsigned short* bhp = bh0 + (u + 1) * 8192;
            const unsigned short* blp = bl0 + (u + 1) * 8192;
            #pragma unroll
            for (int t = 0; t < 4; ++t) {
                NH[t] = *reinterpret_cast<const u32x4*>(bhp + t * 512);
                NL[t] = *reinterpret_cast<const u32x4*>(blp + t * 512);
            }
        }
        const int ao = abase + (u / 3) * 104 + (u % 3) * 32;
        u32x4 AH[4], AL[4];
        #pragma unroll
        for (int pt = 0; pt < 4; ++pt) {
            AH[pt] = *reinterpret_cast<const u32x4*>(&xT[ao + pt * 1664]);
            AL[pt] = *reinterpret_cast<const u32x4*>(&xT[7072 + ao + pt * 1664]);
        }
        #pragma unroll
        for (int pt = 0; pt < 4; ++pt) {
            bf16x8 Ah = __builtin_bit_cast(bf16x8, AH[pt]);
            bf16x8 Al = __builtin_bit_cast(bf16x8, AL[pt]);
            #pragma unroll
            for (int t = 0; t < 4; ++t) {
                bf16x8 Bh = __builtin_bit_cast(bf16x8, BH[t]);
                bf16x8 Bl = __builtin_bit_cast(bf16x8, BL[t]);
                acc[pt][t] = __builtin_amdgcn_mfma_f32_16x16x32_bf16(Ah, Bh, acc[pt][t], 0, 0, 0);
                acc[pt][t] = __builtin_amdgcn_mfma_f32_16x16x32_bf16(Ah, Bl, acc[pt][t], 0, 0, 0);
                acc[pt][t] = __builtin_amdgcn_mfma_f32_16x16x32_bf16(Al, Bh, acc[pt][t], 0, 0, 0);
            }
        }
    }

    // ---- per-row top-2 (wave-local over 64 o's, then cross-wave via LDS)
    #pragma unroll
    for (int pt = 0; pt < 4; ++pt) {
        #pragma unroll
        for (int i = 0; i < 4; ++i) {
            float a0 = acc[pt][0][i], a1 = acc[pt][1][i], a2 = acc[pt][2][i], a3 = acc[pt][3][i];
            float m1 = fmaxf(a0, a1), m2 = fminf(a0, a1);
            m2 = fmaxf(m2, fminf(m1, a2)); m1 = fmaxf(m1, a2);
            m2 = fmaxf(m2, fminf(m1, a3)); m1 = fmaxf(m1, a3);
            #pragma unroll
            for (int off = 1; off <= 8; off <<= 1) {
                float o1 = __shfl_xor(m1, off), o2 = __shfl_xor(m2, off);
                m2 = fmaxf(fminf(m1, o1), fmaxf(m2, o2));
                m1 = fmaxf(m1, o1);
            }
            if (r == 0) { int p = 16 * pt + 4 * q + i; wm1[wv][p] = m1; wm2[wv][p] = m2; }
        }
    }
    __syncthreads();
    if (tid < 64) {
        const int p = tid;
        float M1 = wm1[0][p], M2 = wm2[0][p];
        #pragma unroll
        for (int w2 = 1; w2 < 4; ++w2) {
            float c1 = wm1[w2][p], c2 = wm2[w2][p];
            M2 = fmaxf(fminf(M1, c1), fmaxf(M2, c2));
            M1 = fmaxf(M1, c1);
        }
        bool amb = (M1 - M2) < TAU;
        if (amb && p < Wo_) {
            int n = (b * Ho_ + ho) * Wo_ + p;
            int pos = atomicAdd(acnt, 1);
            if (pos < ACAP) ambig[pos] = n;
        }
        rowM1[p] = amb ? __builtin_inff() : M1;   // INF suppresses appends for ambiguous rows
    }
    __syncthreads();

    // ---- winner appends (exact equality vs block max; ties append all, like s==s.max())
    #pragma unroll
    for (int pt = 0; pt < 4; ++pt) {
        #pragma unroll
        for (int i = 0; i < 4; ++i) {
            const int p = 16 * pt + 4 * q + i;
            const float M = rowM1[p];
            if (p < Wo_) {
                const int n = (b * Ho_ + ho) * Wo_ + p;
                #pragma unroll
                for (int t = 0; t < 4; ++t) {
                    float v = acc[pt][t][i];
                    if (v == M) {
                        int o = 64 * wv + 16 * t + r;
                        int pos = atomicAdd(&count[o], 1);
                        if (pos < cap) { lw_n[o * cap + pos] = n; lw_s[o * cap + pos] = v; }
                    }
                }
            }
        }
    }

    // ---- y stores: acc reg vector = 4 consecutive wo for one o -> dwordx4
    #pragma unroll
    for (int pt = 0; pt < 4; ++pt) {
        const int wo = 16 * pt + 4 * q;
        if (wo < Wo_) {                       // skips (pt=3,q=3) = wo 60..63
            #pragma unroll
            for (int t = 0; t < 4; ++t) {
                const int o = 64 * wv + 16 * t + r;
                f4 v = { acc[pt][t].x, acc[pt][t].y, acc[pt][t].z, acc[pt][t].w };
                *reinterpret_cast<f4*>(y + ((size_t)(b * O_ + o) * Ho_ + ho) * (size_t)Wo_ + wo) = v;
            }
        }
    }
}

// ---- fallback: exact fp32 re-resolve of ambiguous rows ----
__global__ void fallback_kernel(const float* __restrict__ x, const float* __restrict__ w,
                                const int* __restrict__ acnt, const int* __restrict__ ambig,
                                int* __restrict__ count, int* __restrict__ lw_n,
                                float* __restrict__ lw_s, int cap) {
    __shared__ float xrow[Dd];
    __shared__ float red[256];
    int cnt = *acnt; if (cnt > ACAP) cnt = ACAP;
    for (int idx = blockIdx.x; idx < cnt; idx += gridDim.x) {
        const int n = ambig[idx];
        const int bb = n / 3600, rem = n % 3600, hh = rem / 60, ww2 = rem % 60;
        for (int k = threadIdx.x; k < Dd; k += 256) {
            int c = k / 25, rr = k % 25, i = rr / 5, j = rr % 5;
            xrow[k] = x[(((size_t)bb * C_ + c) * Hh + hh + i) * Ww + ww2 + j];
        }
        __syncthreads();
        const int o = threadIdx.x;
        const float* wr = w + (size_t)o * Dd;
        float s = 0.f;
        #pragma unroll 4
        for (int k = 0; k < Dd; ++k) s = fmaf(xrow[k], wr[k], s);
        red[o] = s;
        __syncthreads();
        #pragma unroll
        for (int st = 128; st >= 1; st >>= 1) {
            if (o < st) red[o] = fmaxf(red[o], red[o + st]);
            __syncthreads();
        }
        const float mx = red[0];
        if (s == mx) {
            int pos = atomicAdd(&count[o], 1);
            if (pos < cap) { lw_n[o * cap + pos] = n; lw_s[o * cap + pos] = s; }
        }
        __syncthreads();
    }
}

// ---- phase 2a: per-slice partial sums (4 slices per o) ----
__global__ void delta_part_kernel(const float* __restrict__ x,
                                  const int* __restrict__ count, const int* __restrict__ lw_n,
                                  const float* __restrict__ lw_s, float* __restrict__ partial,
                                  float* __restrict__ ssum_part, int cap) {
    const int o   = blockIdx.x >> 2;
    const int sl  = blockIdx.x & 3;
    const int tid = threadIdx.x;
    int cnt = count[o]; if (cnt > cap) cnt = cap;
    const int e0 = (cnt * sl) >> 2;
    const int e1 = (cnt * (sl + 1)) >> 2;

    const int d0 = tid;
    const int c0 = d0 / 25, r0 = d0 % 25, i0 = r0 / 5, j0 = r0 % 5;
    const bool has1 = (tid < Dd - 256);
    const int dd1 = has1 ? tid + 256 : 0;
    const int c1 = dd1 / 25, r1 = dd1 % 25, i1 = r1 / 5, j1 = r1 % 5;

    const int* ln = lw_n + (size_t)o * cap;
    const float* ls = lw_s + (size_t)o * cap;

    float acc0 = 0.f, acc1 = 0.f, ssum = 0.f;
    int   nn = (e0 < e1) ? ln[e0] : 0;
    float sn = (e0 < e1) ? ls[e0] : 0.f;
    for (int e = e0; e < e1; ++e) {
        const int n = nn; const float s = sn;
        if (e + 1 < e1) { nn = ln[e + 1]; sn = ls[e + 1]; }
        const int bb = n / 3600;
        const int rem = n - bb * 3600;
        const int hh = rem / 60;
        const int ww2 = rem - hh * 60;
        ssum += s;
        const float* xb = x + (size_t)bb * (C_ * Hh * Ww);
        acc0 += s * xb[(c0 * Hh + hh + i0) * Ww + ww2 + j0];
        if (has1) acc1 += s * xb[(c1 * Hh + hh + i1) * Ww + ww2 + j1];
    }
    float* pp = partial + ((size_t)o * 4 + sl) * Dd;
    pp[tid] = acc0;
    if (has1) pp[tid + 256] = acc1;
    if (tid == 0) ssum_part[o * 4 + sl] = ssum;
}

// ---- phase 2b: reduce partials, apply -ssum/N * w ----
__global__ void delta_reduce_kernel(const float* __restrict__ w, const float* __restrict__ partial,
                                    const float* __restrict__ ssum_part,
                                    float* __restrict__ dout) {
    const int o = blockIdx.x, tid = threadIdx.x;
    const float ssum = ssum_part[o * 4] + ssum_part[o * 4 + 1]
                     + ssum_part[o * 4 + 2] + ssum_part[o * 4 + 3];
    const float invN = 1.0f / (float)Nn;
    const float* pp = partial + (size_t)o * 4 * Dd;
    float a0 = pp[tid] + pp[Dd + tid] + pp[2 * Dd + tid] + pp[3 * Dd + tid];
    dout[NY + (size_t)o * Dd + tid] = a0 * invN - ssum * invN * w[o * Dd + tid];
    if (tid < Dd - 256) {
        const int t2 = tid + 256;
        float a1 = pp[t2] + pp[Dd + t2] + pp[2 * Dd + t2] + pp[3 * Dd + t2];
        dout[NY + (size_t)o * Dd + t2] = a1 * invN - ssum * invN * w[o * Dd + t2];
    }
}

extern "C" void kernel_launch(void* const* d_in, const int* in_sizes, int n_in,
                              void* d_out, int out_size, void* d_ws, size_t ws_size,
                              hipStream_t stream) {
    (void)in_sizes; (void)n_in; (void)out_size;
    const float* x = (const float*)d_in[0];
    const float* w = (const float*)d_in[1];
    float* out = (float*)d_out;

    char* ws = (char*)d_ws;
    int*            count     = (int*)ws;                          // @0         (1,024 B)
    int*            acnt      = (int*)(ws + 1024);                 // @1,024     (64 B)
    int*            ambig     = (int*)(ws + 1088);                 // @1,088     (65,536 B)
    unsigned short* wpkH      = (unsigned short*)(ws + 66624);     // @66,624    (245,760 B)
    unsigned short* wpkL      = (unsigned short*)(ws + 312384);    // @312,384   (245,760 B)
    float*          partial   = (float*)(ws + 558144);             // @558,144   (1,638,400 B)
    float*          ssum_part = (float*)(ws + 2196544);            // @2,196,544 (4,096 B)
    const size_t base = 2200640;

    size_t avail = (ws_size > base) ? (ws_size - base) : 0;
    long long cap_ll = (long long)(avail / ((size_t)O_ * 8));
    int cap = (int)(cap_ll > 4096 ? 4096 : (cap_ll < 1 ? 1 : cap_ll));

    int*   lw_n = (int*)(ws + base);
    float* lw_s = (float*)(ws + base + (size_t)O_ * cap * 4);

    prep_kernel<<<dim3(60), dim3(256), 0, stream>>>(w, wpkH, wpkL, count, acnt);
    conv_mfma_kernel<<<dim3(B_ * Ho_), dim3(256), 0, stream>>>(x, wpkH, wpkL, out, count, lw_n, lw_s,
                                                               acnt, ambig, cap);
    fallback_kernel<<<dim3(256), dim3(256), 0, stream>>>(x, w, acnt, ambig, count, lw_n, lw_s, cap);
    delta_part_kernel<<<dim3(O_ * 4), dim3(256), 0, stream>>>(x, count, lw_n, lw_s, partial, ssum_part, cap);
    delta_reduce_kernel<<<dim3(O_), dim3(256), 0, stream>>>(w, partial, ssum_part, out);
}